// Round 1
// baseline (265.775 us; speedup 1.0000x reference)
//
#include <hip/hip_runtime.h>
#include <hip/hip_bf16.h>
#include <math.h>

#define B_    64
#define TQ    32
#define TD    4096
#define HDIM  300
#define NB    29      // histogram bins
#define NFEAT 30      // 29 bins + exact-match feature
#define DTILE 256
#define NCHUNK 16     // TD / DTILE
#define HC    60      // h chunk size
#define NHC   5       // HDIM / HC
#define NF4   15      // HC / 4 float4 per row-chunk

// bin upper bounds: jnp.linspace(-1,1,30)[1:], ub[k] = -1 + 2(k+1)/29, ub[28] = 1.0
__device__ __forceinline__ float ubf(int k) {
    return (float)(-1.0 + (2.0 * (double)(k + 1)) / 29.0);
}

// ---------------- norms: one wave per embedding row ----------------
__global__ void k_norms(const int* __restrict__ qsent, const int* __restrict__ sent,
                        const float* __restrict__ emb,
                        float* __restrict__ invq, float* __restrict__ invd) {
    int wave = (int)((blockIdx.x * blockDim.x + threadIdx.x) >> 6);
    int lane = threadIdx.x & 63;
    const int NQ = B_ * TQ;
    const int NROWS = NQ + B_ * TD;
    if (wave >= NROWS) return;
    int tok = (wave < NQ) ? qsent[wave] : sent[wave - NQ];
    const float* row = emb + (size_t)tok * HDIM;
    float4 v = *(const float4*)(row + lane * 4);          // 64 lanes cover h 0..255
    float s = v.x * v.x + v.y * v.y + v.z * v.z + v.w * v.w;
    if (lane < 11) {                                      // h 256..299
        float4 w = *(const float4*)(row + 256 + lane * 4);
        s += w.x * w.x + w.y * w.y + w.z * w.z + w.w * w.w;
    }
#pragma unroll
    for (int m = 1; m < 64; m <<= 1) s += __shfl_xor(s, m, 64);
    if (lane == 0) {
        float r = 1.0f / (sqrtf(s + 1e-7f) + 1e-7f);
        if (wave < NQ) invq[wave] = r; else invd[wave - NQ] = r;
    }
}

// ---------------- main: sim GEMM + histogram ----------------
// block: 256 threads = 4 waves; tile 32q x 256d; wave w owns q rows w*8..w*8+7,
// lane owns d = lane*4..lane*4+3.
__global__ __launch_bounds__(256) void k_main(
        const int* __restrict__ sent, const int* __restrict__ qsent,
        const float* __restrict__ emb, const float* __restrict__ invq,
        const float* __restrict__ invd, unsigned* __restrict__ ghist) {
    __shared__ __align__(16) float dxT[HC][DTILE];   // 61.4 KB, swizzled transpose
    __shared__ __align__(16) float qxT[HC][TQ];      // 7.7 KB, swizzled transpose
    __shared__ int      toks[DTILE];
    __shared__ int      qtk[TQ];
    __shared__ float    s_iq[TQ];
    __shared__ float    s_id[DTILE];
    __shared__ unsigned s_hist[TQ * NFEAT];

    const int b   = blockIdx.x >> 4;
    const int d0  = (blockIdx.x & 15) * DTILE;
    const int tid = threadIdx.x;
    const int wid = tid >> 6;
    const int lane = tid & 63;

    for (int i = tid; i < TQ * NFEAT; i += 256) s_hist[i] = 0u;
    if (tid < DTILE) {
        toks[tid] = sent[b * TD + d0 + tid];
        s_id[tid] = invd[b * TD + d0 + tid];
    }
    if (tid < TQ) {
        qtk[tid] = qsent[b * TQ + tid];
        s_iq[tid] = invq[b * TQ + tid];
    }
    __syncthreads();

    float acc[8][4];
#pragma unroll
    for (int qi = 0; qi < 8; ++qi)
#pragma unroll
        for (int di = 0; di < 4; ++di) acc[qi][di] = 0.f;

    const int q0 = wid * 8;

    for (int hc = 0; hc < NHC; ++hc) {
        const int hbase = hc * HC;
        // ---- stage dx: 256 rows x 60 cols, transposed, float4-slot XOR swizzle
        for (int it = 0; it < NF4; ++it) {          // 15*256 == 3840 exactly
            int i = it * 256 + tid;
            int d = i / NF4, jf = i - d * NF4;
            float4 v = *(const float4*)(emb + (size_t)toks[d] * HDIM + hbase + jf * 4);
            int d4 = d >> 2, dl = d & 3;
            float vv[4] = {v.x, v.y, v.z, v.w};
#pragma unroll
            for (int j = 0; j < 4; ++j) {
                int h = jf * 4 + j;
                dxT[h][(((d4 ^ (h & 15)) << 2) | dl)] = vv[j];
            }
        }
        // ---- stage qx: 32 rows x 60 cols, transposed, q XOR swizzle (bits 3..4)
        for (int it = 0; it < 2; ++it) {
            int i = it * 256 + tid;
            if (i < TQ * NF4) {
                int q = i / NF4, jf = i - q * NF4;
                float4 v = *(const float4*)(emb + (size_t)qtk[q] * HDIM + hbase + jf * 4);
                float vv[4] = {v.x, v.y, v.z, v.w};
#pragma unroll
                for (int j = 0; j < 4; ++j) {
                    int h = jf * 4 + j;
                    qxT[h][q ^ ((h & 3) << 3)] = vv[j];
                }
            }
        }
        __syncthreads();

        // ---- compute: per 4-h step: 8 uniform qx b128 + 4 lane-wise dx b128, 128 FMA/thread
#pragma unroll 3
        for (int h4 = 0; h4 < NF4; ++h4) {
            float qr[4][8], dr[4][4];
#pragma unroll
            for (int j = 0; j < 4; ++j) {
                int h = h4 * 4 + j;
                int qp = q0 ^ ((h & 3) << 3);                    // multiple of 8
                float4 a = *(const float4*)&qxT[h][qp];
                float4 c = *(const float4*)&qxT[h][qp + 4];
                qr[j][0] = a.x; qr[j][1] = a.y; qr[j][2] = a.z; qr[j][3] = a.w;
                qr[j][4] = c.x; qr[j][5] = c.y; qr[j][6] = c.z; qr[j][7] = c.w;
                float4 dv = *(const float4*)&dxT[h][(lane ^ (h & 15)) << 2];
                dr[j][0] = dv.x; dr[j][1] = dv.y; dr[j][2] = dv.z; dr[j][3] = dv.w;
            }
#pragma unroll
            for (int j = 0; j < 4; ++j)        // h ascending: sequential summation
#pragma unroll
                for (int qi = 0; qi < 8; ++qi)
#pragma unroll
                    for (int di = 0; di < 4; ++di)
                        acc[qi][di] = fmaf(qr[j][qi], dr[j][di], acc[qi][di]);
        }
        __syncthreads();
    }

    // ---- epilogue: sim -> bins
#pragma unroll 1
    for (int qi = 0; qi < 8; ++qi) {
        int q = q0 + qi;
        float iq = s_iq[q];
#pragma unroll 1
        for (int di = 0; di < 4; ++di) {
            int d = (lane << 2) | di;
            if (toks[d] == 0) continue;       // masked doc: +1e7 -> dropped everywhere
            float sim = acc[qi][di] * iq * s_id[d];
            if (sim > 0.999f && sim < 1.001f) {
                // only exact token matches land here; true sim < 1.0 strictly -> bin 28
                atomicAdd(&s_hist[q * NFEAT + 28], 1u);
                atomicAdd(&s_hist[q * NFEAT + 29], 1u);   // exact-match feature
            } else {
                int idx = (int)((sim + 1.0f) * 14.5f);    // guess, then exact fixup
                idx = idx < 0 ? 0 : (idx > NB ? NB : idx);
                while (idx < NB && sim >= ubf(idx)) ++idx;
                while (idx > 0 && sim < ubf(idx - 1)) --idx;
                if (idx < NB) atomicAdd(&s_hist[q * NFEAT + idx], 1u);
            }
        }
    }
    __syncthreads();
    for (int i = tid; i < TQ * NFEAT; i += 256) {
        unsigned v = s_hist[i];
        if (v) atomicAdd(&ghist[b * TQ * NFEAT + i], v);
    }
}

// ---------------- finish: log + MLP + gate softmax ----------------
__global__ void k_finish(const unsigned* __restrict__ ghist,
                         const int* __restrict__ qsent, const float* __restrict__ idf,
                         const float* __restrict__ w1, const float* __restrict__ b1,
                         const float* __restrict__ w2, const float* __restrict__ b2,
                         const float* __restrict__ gw, const float* __restrict__ ow,
                         const float* __restrict__ ob, float* __restrict__ out) {
    int b = blockIdx.x;
    int lane = threadIdx.x;   // 64 threads, lanes 0..31 active
    float ffw = 0.f;
    float logit = -3.0e38f;
    if (lane < TQ) {
        const unsigned* h = ghist + (b * TQ + lane) * NFEAT;
        float f[NFEAT];
        for (int k = 0; k < NFEAT; ++k) f[k] = logf((float)h[k] + 1.0f);
        float s2 = b2[0];
        for (int n = 0; n < 5; ++n) {
            float s = b1[n];
            for (int k = 0; k < NFEAT; ++k) s = fmaf(f[k], w1[k * 5 + n], s);
            s2 = fmaf(tanhf(s), w2[n], s2);
        }
        ffw = tanhf(s2);
        int qt = qsent[b * TQ + lane];
        logit = idf[b * TQ + lane] * gw[0] + (qt == 0 ? -1e7f : 0.f);
    }
    float m = logit;
#pragma unroll
    for (int t = 1; t < 64; t <<= 1) m = fmaxf(m, __shfl_xor(m, t, 64));
    float e = expf(logit - m);            // inactive lanes -> exp(-inf) = 0
    float se = e, sw = e * ffw;
#pragma unroll
    for (int t = 1; t < 64; t <<= 1) {
        se += __shfl_xor(se, t, 64);
        sw += __shfl_xor(sw, t, 64);
    }
    if (lane == 0) out[b] = (sw / se) * ow[0] + ob[0];
}

extern "C" void kernel_launch(void* const* d_in, const int* in_sizes, int n_in,
                              void* d_out, int out_size, void* d_ws, size_t ws_size,
                              hipStream_t stream) {
    const int*   sent  = (const int*)d_in[0];
    const int*   qsent = (const int*)d_in[1];
    const float* idf   = (const float*)d_in[2];
    const float* emb   = (const float*)d_in[3];
    const float* w1    = (const float*)d_in[4];
    const float* b1    = (const float*)d_in[5];
    const float* w2    = (const float*)d_in[6];
    const float* b2    = (const float*)d_in[7];
    const float* gw    = (const float*)d_in[8];
    const float* ow    = (const float*)d_in[9];
    const float* ob    = (const float*)d_in[10];
    float* out = (float*)d_out;

    char* ws = (char*)d_ws;
    unsigned* ghist = (unsigned*)ws;                                 // 64*32*30 u32 = 240 KB
    float* invq = (float*)(ws + (size_t)B_ * TQ * NFEAT * 4);        // 2048 f
    float* invd = invq + B_ * TQ;                                    // 262144 f

    hipMemsetAsync(ghist, 0, (size_t)B_ * TQ * NFEAT * 4, stream);

    int nrows = B_ * TQ + B_ * TD;        // 264192, divisible by 4 waves/block
    k_norms<<<nrows / 4, 256, 0, stream>>>(qsent, sent, emb, invq, invd);
    k_main<<<B_ * NCHUNK, 256, 0, stream>>>(sent, qsent, emb, invq, invd, ghist);
    k_finish<<<B_, 64, 0, stream>>>(ghist, qsent, idf, w1, b1, w2, b2, gw, ow, ob, out);
}

// Round 2
// 188.378 us; speedup vs baseline: 1.4109x; 1.4109x over previous
//
#include <hip/hip_runtime.h>
#include <hip/hip_bf16.h>
#include <math.h>

#define B_    64
#define TQ    32
#define TD    4096
#define HDIM  300
#define NB    29      // histogram bins
#define NFEAT 30      // 29 bins + exact-match feature
#define DTILE 256
#define NCHUNK 16     // TD / DTILE
#define HC    60      // h chunk size
#define NHC   5       // HDIM / HC
#define THREADS 512

// bin upper bounds: jnp.linspace(-1,1,30)[1:], ub[k] = -1 + 2(k+1)/29
__device__ __forceinline__ float ubf(int k) {
    return (float)(-1.0 + (2.0 * (double)(k + 1)) / 29.0);
}

// ---------------- main: fused norms + sim GEMM + histogram ----------------
// 512 threads = 8 waves; tile 32q x 256d.
// Wave w: q rows (w&3)*8..+7, d half (w>>2): lane owns d = half*128 + lane*2 (+0,+1).
// Staging: thread t stages d-row (t&255), h-half (t>>8); threads<64 also stage q rows.
__global__ __launch_bounds__(THREADS, 4) void k_main(
        const int* __restrict__ sent, const int* __restrict__ qsent,
        const float* __restrict__ emb, unsigned* __restrict__ ghist) {
    __shared__ __align__(16) float dxT[HC][DTILE];   // 61.4 KB transposed tile
    __shared__ __align__(16) float qxT[HC][TQ];      // 7.7 KB
    __shared__ int      toks[DTILE];
    __shared__ int      qtk[TQ];
    __shared__ float    s_iq[TQ];
    __shared__ float    s_id[DTILE];
    __shared__ unsigned s_hist[TQ * NFEAT];
    __shared__ float    pnd[2][DTILE];               // norm partials
    __shared__ float    pnq[2][TQ];

    const int b    = blockIdx.x >> 4;
    const int d0   = (blockIdx.x & 15) * DTILE;
    const int tid  = threadIdx.x;
    const int wid  = tid >> 6;
    const int lane = tid & 63;

    if (tid < DTILE) toks[tid] = sent[b * TD + d0 + tid];
    if (tid < TQ)    qtk[tid]  = qsent[b * TQ + tid];
    __syncthreads();

    // staging roles (uniform per wave: dhalf = tid>>8)
    const int drow  = tid & 255;
    const int dhalf = tid >> 8;              // 0: h 0..31 of chunk, 1: h 32..59
    const int nfd   = 8 - dhalf;             // 8 or 7 float4 per chunk
    const int hofs  = dhalf * 32;
    const float* dptr0 = emb + (size_t)toks[drow] * HDIM + hofs;
    const bool  doq   = (tid < 64);
    const int   qrow  = tid & 31;
    const int   qhalf = (tid >> 5) & 1;
    const int   nfq   = 8 - qhalf;
    const int   qhofs = qhalf * 32;
    const float* qptr0 = doq ? (emb + (size_t)qtk[qrow] * HDIM + qhofs) : emb;

    float nd = 0.f, nq = 0.f;                // per-thread norm partials

    // compute roles
    const int q0  = (wid & 3) * 8;
    const int myd = ((wid >> 2) << 7) + lane * 2;

    float acc[8][2];
#pragma unroll
    for (int qi = 0; qi < 8; ++qi) { acc[qi][0] = 0.f; acc[qi][1] = 0.f; }

    for (int hc = 0; hc < NHC; ++hc) {
        const int hb = hc * HC;
        // ---- stage dx: column writes, lanes = consecutive rows -> conflict-free
        {
            const float* p = dptr0 + hb;
#pragma unroll
            for (int jf = 0; jf < 8; ++jf) {
                if (jf >= nfd) break;                     // uniform per wave
                float4 v = *(const float4*)(p + jf * 4);
                int h = hofs + jf * 4;
                dxT[h + 0][drow] = v.x; dxT[h + 1][drow] = v.y;
                dxT[h + 2][drow] = v.z; dxT[h + 3][drow] = v.w;
                nd = fmaf(v.x, v.x, nd); nd = fmaf(v.y, v.y, nd);
                nd = fmaf(v.z, v.z, nd); nd = fmaf(v.w, v.w, nd);
            }
        }
        // ---- stage qx (wave 0 only)
        if (doq) {
            const float* p = qptr0 + hb;
#pragma unroll
            for (int jf = 0; jf < 8; ++jf) {
                if (jf >= nfq) break;
                float4 v = *(const float4*)(p + jf * 4);
                int h = qhofs + jf * 4;
                qxT[h + 0][qrow] = v.x; qxT[h + 1][qrow] = v.y;
                qxT[h + 2][qrow] = v.z; qxT[h + 3][qrow] = v.w;
                nq = fmaf(v.x, v.x, nq); nq = fmaf(v.y, v.y, nq);
                nq = fmaf(v.z, v.z, nq); nq = fmaf(v.w, v.w, nq);
            }
        }
        __syncthreads();

        // ---- compute: per h: 1 lane-contiguous float2 (dx) + 2 uniform float4 (qx), 16 FMA
#pragma unroll 3
        for (int h4 = 0; h4 < 15; ++h4) {
#pragma unroll
            for (int j = 0; j < 4; ++j) {
                const int h = h4 * 4 + j;
                float2 dv = *(const float2*)&dxT[h][myd];
                float4 a  = *(const float4*)&qxT[h][q0];
                float4 c  = *(const float4*)&qxT[h][q0 + 4];
                acc[0][0] = fmaf(a.x, dv.x, acc[0][0]); acc[0][1] = fmaf(a.x, dv.y, acc[0][1]);
                acc[1][0] = fmaf(a.y, dv.x, acc[1][0]); acc[1][1] = fmaf(a.y, dv.y, acc[1][1]);
                acc[2][0] = fmaf(a.z, dv.x, acc[2][0]); acc[2][1] = fmaf(a.z, dv.y, acc[2][1]);
                acc[3][0] = fmaf(a.w, dv.x, acc[3][0]); acc[3][1] = fmaf(a.w, dv.y, acc[3][1]);
                acc[4][0] = fmaf(c.x, dv.x, acc[4][0]); acc[4][1] = fmaf(c.x, dv.y, acc[4][1]);
                acc[5][0] = fmaf(c.y, dv.x, acc[5][0]); acc[5][1] = fmaf(c.y, dv.y, acc[5][1]);
                acc[6][0] = fmaf(c.z, dv.x, acc[6][0]); acc[6][1] = fmaf(c.z, dv.y, acc[6][1]);
                acc[7][0] = fmaf(c.w, dv.x, acc[7][0]); acc[7][1] = fmaf(c.w, dv.y, acc[7][1]);
            }
        }
        __syncthreads();   // before next chunk overwrites dxT/qxT
    }

    // ---- finalize norms (deterministic 2-partial sum), init hist
    pnd[dhalf][drow] = nd;
    if (doq) pnq[qhalf][qrow] = nq;
    __syncthreads();
    if (tid < DTILE) {
        float s = pnd[0][tid] + pnd[1][tid];
        s_id[tid] = 1.0f / (sqrtf(s + 1e-7f) + 1e-7f);
    } else if (tid < DTILE + TQ) {
        int q = tid - DTILE;
        float s = pnq[0][q] + pnq[1][q];
        s_iq[q] = 1.0f / (sqrtf(s + 1e-7f) + 1e-7f);
    }
    for (int i = tid; i < TQ * NFEAT; i += THREADS) s_hist[i] = 0u;
    __syncthreads();

    // ---- epilogue: sim -> bins
#pragma unroll 1
    for (int qi = 0; qi < 8; ++qi) {
        int q = q0 + qi;
        float iq = s_iq[q];
#pragma unroll 1
        for (int di = 0; di < 2; ++di) {
            int dl = myd + di;
            if (toks[dl] == 0) continue;      // masked doc: +1e7 -> dropped everywhere
            float sim = acc[qi][di] * iq * s_id[dl];
            if (sim > 0.999f && sim < 1.001f) {
                // only exact token matches land here; true sim < 1.0 strictly -> bin 28
                atomicAdd(&s_hist[q * NFEAT + 28], 1u);
                atomicAdd(&s_hist[q * NFEAT + 29], 1u);   // exact-match feature
            } else {
                int idx = (int)((sim + 1.0f) * 14.5f);    // guess, then exact fixup
                idx = idx < 0 ? 0 : (idx > NB ? NB : idx);
                while (idx < NB && sim >= ubf(idx)) ++idx;
                while (idx > 0 && sim < ubf(idx - 1)) --idx;
                if (idx < NB) atomicAdd(&s_hist[q * NFEAT + idx], 1u);
            }
        }
    }
    __syncthreads();
    for (int i = tid; i < TQ * NFEAT; i += THREADS) {
        unsigned v = s_hist[i];
        if (v) atomicAdd(&ghist[b * TQ * NFEAT + i], v);
    }
}

// ---------------- finish: log + MLP + gate softmax ----------------
__global__ void k_finish(const unsigned* __restrict__ ghist,
                         const int* __restrict__ qsent, const float* __restrict__ idf,
                         const float* __restrict__ w1, const float* __restrict__ b1,
                         const float* __restrict__ w2, const float* __restrict__ b2,
                         const float* __restrict__ gw, const float* __restrict__ ow,
                         const float* __restrict__ ob, float* __restrict__ out) {
    int b = blockIdx.x;
    int lane = threadIdx.x;   // 64 threads, lanes 0..31 active
    float ffw = 0.f;
    float logit = -3.0e38f;
    if (lane < TQ) {
        const unsigned* h = ghist + (b * TQ + lane) * NFEAT;
        float f[NFEAT];
        for (int k = 0; k < NFEAT; ++k) f[k] = logf((float)h[k] + 1.0f);
        float s2 = b2[0];
        for (int n = 0; n < 5; ++n) {
            float s = b1[n];
            for (int k = 0; k < NFEAT; ++k) s = fmaf(f[k], w1[k * 5 + n], s);
            s2 = fmaf(tanhf(s), w2[n], s2);
        }
        ffw = tanhf(s2);
        int qt = qsent[b * TQ + lane];
        logit = idf[b * TQ + lane] * gw[0] + (qt == 0 ? -1e7f : 0.f);
    }
    float m = logit;
#pragma unroll
    for (int t = 1; t < 64; t <<= 1) m = fmaxf(m, __shfl_xor(m, t, 64));
    float e = expf(logit - m);            // inactive lanes -> exp(-inf) = 0
    float se = e, sw = e * ffw;
#pragma unroll
    for (int t = 1; t < 64; t <<= 1) {
        se += __shfl_xor(se, t, 64);
        sw += __shfl_xor(sw, t, 64);
    }
    if (lane == 0) out[b] = (sw / se) * ow[0] + ob[0];
}

extern "C" void kernel_launch(void* const* d_in, const int* in_sizes, int n_in,
                              void* d_out, int out_size, void* d_ws, size_t ws_size,
                              hipStream_t stream) {
    const int*   sent  = (const int*)d_in[0];
    const int*   qsent = (const int*)d_in[1];
    const float* idf   = (const float*)d_in[2];
    const float* emb   = (const float*)d_in[3];
    const float* w1    = (const float*)d_in[4];
    const float* b1    = (const float*)d_in[5];
    const float* w2    = (const float*)d_in[6];
    const float* b2    = (const float*)d_in[7];
    const float* gw    = (const float*)d_in[8];
    const float* ow    = (const float*)d_in[9];
    const float* ob    = (const float*)d_in[10];
    float* out = (float*)d_out;

    unsigned* ghist = (unsigned*)d_ws;                 // 64*32*30 u32 = 240 KB

    hipMemsetAsync(ghist, 0, (size_t)B_ * TQ * NFEAT * 4, stream);
    k_main<<<B_ * NCHUNK, THREADS, 0, stream>>>(sent, qsent, emb, ghist);
    k_finish<<<B_, 64, 0, stream>>>(ghist, qsent, idf, w1, b1, w2, b2, gw, ow, ob, out);
}